// Round 1
// baseline (338.725 us; speedup 1.0000x reference)
//
#include <hip/hip_runtime.h>

// TreeModel: soft decision tree forward.
// B=8192 rows, D=E=256, H=50 (pad 64), 31 inner nodes, 32 leaves.
// All MFMA in fp16 (v_mfma_f32_16x16x32_f16), fp32 accum + epilogues.

#define B_ROWS 8192
#define HDIM 50
#define HPAD 64

typedef _Float16 f16;
typedef _Float16 f16x8 __attribute__((ext_vector_type(8)));
typedef _Float16 f16x4 __attribute__((ext_vector_type(4)));
typedef float f32x4 __attribute__((ext_vector_type(4)));

static __device__ __forceinline__ f32x4 mfma16(f16x8 a, f16x8 b, f32x4 c) {
  return __builtin_amdgcn_mfma_f32_16x16x32_f16(a, b, c, 0, 0, 0);
}

// ---------------- prep: fp32 -> fp16 cast (vector) ----------------
__global__ void k_cast_f16(const float* __restrict__ in, f16* __restrict__ out, int n4) {
  int i = blockIdx.x * blockDim.x + threadIdx.x;
  if (i < n4) {
    float4 v = reinterpret_cast<const float4*>(in)[i];
    f16x4 o = { (f16)v.x, (f16)v.y, (f16)v.z, (f16)v.w };
    reinterpret_cast<f16x4*>(out)[i] = o;
  }
}

// ---------------- prep: batched transpose-cast with zero pad ----------------
// in: [S][R][C] fp32 ; out: [S][Cp][Rp] fp16, out[s][c][r] = (r<R && c<C) ? in[s][r][c] : 0
__global__ void k_tcast(const float* __restrict__ in, f16* __restrict__ out,
                        int R, int C, int Rp, int Cp) {
  __shared__ float t[32][33];
  const int s = blockIdx.z;
  const int r0 = blockIdx.x * 32, c0 = blockIdx.y * 32;
  const int tx = threadIdx.x, ty = threadIdx.y;
  const float* ip = in + (size_t)s * R * C;
  f16* op = out + (size_t)s * Cp * Rp;
#pragma unroll
  for (int i = 0; i < 4; ++i) {
    int r = r0 + ty + 8 * i, c = c0 + tx;
    t[ty + 8 * i][tx] = (r < R && c < C) ? ip[(size_t)r * C + c] : 0.f;
  }
  __syncthreads();
#pragma unroll
  for (int i = 0; i < 4; ++i) {
    int c = c0 + ty + 8 * i, r = r0 + tx;
    if (c < Cp && r < Rp) op[(size_t)c * Rp + r] = (f16)t[tx][ty + 8 * i];
  }
}

// ---------------- encoder GEMM: out = relu(A @ W + b), A[8192][256] f16, WT[256][256] (n,k) ----------------
__global__ __launch_bounds__(256) void k_enc(const f16* __restrict__ A,
    const f16* __restrict__ WT, const float* __restrict__ bias,
    f16* __restrict__ out) {
  __shared__ f16 At[64][72];
  __shared__ f16 Bt[256][72];
  const int tid = threadIdx.x;
  const int wave = tid >> 6, lane = tid & 63;
  const int grp = lane >> 4, lid = lane & 15;
  const int row0 = blockIdx.x * 64;
  const int sr = tid >> 3, sc = (tid & 7) * 8;

  f32x4 acc[4][4] = {};
  for (int kt = 0; kt < 4; ++kt) {
    const int kb = kt * 64;
#pragma unroll
    for (int p = 0; p < 2; ++p)
      *(f16x8*)&At[p * 32 + sr][sc] =
          *(const f16x8*)&A[(size_t)(row0 + p * 32 + sr) * 256 + kb + sc];
#pragma unroll
    for (int p = 0; p < 8; ++p)
      *(f16x8*)&Bt[p * 32 + sr][sc] =
          *(const f16x8*)&WT[(size_t)(p * 32 + sr) * 256 + kb + sc];
    __syncthreads();
#pragma unroll
    for (int kk = 0; kk < 2; ++kk) {
      f16x8 af[4], bf[4];
#pragma unroll
      for (int m = 0; m < 4; ++m) af[m] = *(const f16x8*)&At[m * 16 + lid][kk * 32 + grp * 8];
#pragma unroll
      for (int n = 0; n < 4; ++n) bf[n] = *(const f16x8*)&Bt[wave * 64 + n * 16 + lid][kk * 32 + grp * 8];
#pragma unroll
      for (int m = 0; m < 4; ++m)
#pragma unroll
        for (int n = 0; n < 4; ++n) acc[m][n] = mfma16(af[m], bf[n], acc[m][n]);
    }
    __syncthreads();
  }
#pragma unroll
  for (int n = 0; n < 4; ++n) {
    const int col = wave * 64 + n * 16 + lid;
    const float bv = bias[col];
#pragma unroll
    for (int m = 0; m < 4; ++m)
#pragma unroll
      for (int r = 0; r < 4; ++r) {
        const int row = row0 + m * 16 + grp * 4 + r;
        float v = acc[m][n][r] + bv;
        out[(size_t)row * 256 + col] = (f16)(v > 0.f ? v : 0.f);
      }
  }
}

// ---------------- leaf: y_leaf[row][leaf] = relu(emb @ lfW1[l] + b1) . W2 + b2 ----------------
__global__ __launch_bounds__(256) void k_leaf(const f16* __restrict__ emb,
    const f16* __restrict__ W1T_all, const float* __restrict__ b1_all,
    const float* __restrict__ W2_all, const float* __restrict__ b2_all,
    float* __restrict__ y_leaf) {
  __shared__ f16 At[64][72];
  __shared__ f16 Bt[256][72];
  __shared__ float red[4][64];
  const int tid = threadIdx.x;
  const int wave = tid >> 6, lane = tid & 63;
  const int grp = lane >> 4, lid = lane & 15;
  const int row0 = blockIdx.x * 64;
  const int leaf = blockIdx.y;
  const f16* WT = W1T_all + (size_t)leaf * 256 * 256;
  const float* b1 = b1_all + leaf * 256;
  const float* W2 = W2_all + leaf * 256;
  const int sr = tid >> 3, sc = (tid & 7) * 8;

  f32x4 acc[4][4] = {};
  for (int kt = 0; kt < 4; ++kt) {
    const int kb = kt * 64;
#pragma unroll
    for (int p = 0; p < 2; ++p)
      *(f16x8*)&At[p * 32 + sr][sc] =
          *(const f16x8*)&emb[(size_t)(row0 + p * 32 + sr) * 256 + kb + sc];
#pragma unroll
    for (int p = 0; p < 8; ++p)
      *(f16x8*)&Bt[p * 32 + sr][sc] =
          *(const f16x8*)&WT[(size_t)(p * 32 + sr) * 256 + kb + sc];
    __syncthreads();
#pragma unroll
    for (int kk = 0; kk < 2; ++kk) {
      f16x8 af[4], bf[4];
#pragma unroll
      for (int m = 0; m < 4; ++m) af[m] = *(const f16x8*)&At[m * 16 + lid][kk * 32 + grp * 8];
#pragma unroll
      for (int n = 0; n < 4; ++n) bf[n] = *(const f16x8*)&Bt[wave * 64 + n * 16 + lid][kk * 32 + grp * 8];
#pragma unroll
      for (int m = 0; m < 4; ++m)
#pragma unroll
        for (int n = 0; n < 4; ++n) acc[m][n] = mfma16(af[m], bf[n], acc[m][n]);
    }
    __syncthreads();
  }
  // epilogue: relu(acc+b1)*W2, reduce over 256 cols
  float rs[16];
#pragma unroll
  for (int i = 0; i < 16; ++i) rs[i] = 0.f;
#pragma unroll
  for (int n = 0; n < 4; ++n) {
    const int col = wave * 64 + n * 16 + lid;
    const float bv = b1[col];
    const float w2 = W2[col];
#pragma unroll
    for (int m = 0; m < 4; ++m)
#pragma unroll
      for (int r = 0; r < 4; ++r) {
        float v = acc[m][n][r] + bv;
        v = v > 0.f ? v : 0.f;
        rs[m * 4 + r] += v * w2;
      }
  }
#pragma unroll
  for (int mask = 1; mask < 16; mask <<= 1)
#pragma unroll
    for (int i = 0; i < 16; ++i) rs[i] += __shfl_xor(rs[i], mask, 64);
  if (lid == 0)
#pragma unroll
    for (int m = 0; m < 4; ++m)
#pragma unroll
      for (int r = 0; r < 4; ++r) red[wave][m * 16 + grp * 4 + r] = rs[m * 4 + r];
  __syncthreads();
  if (tid < 64) {
    float y = red[0][tid] + red[1][tid] + red[2][tid] + red[3][tid] + b2_all[leaf];
    y_leaf[(size_t)(row0 + tid) * 32 + leaf] = y;
  }
}

// ---------------- inner stage 1: h_all[n][row][0..63] = relu(emb @ inW1[n] + b1) ----------------
__global__ __launch_bounds__(256) void k_hnode(const f16* __restrict__ emb,
    const f16* __restrict__ W1T_all, const float* __restrict__ b1_all,
    f16* __restrict__ h_all) {
  __shared__ f16 At[64][72];
  __shared__ f16 Bt[64][72];
  const int tid = threadIdx.x;
  const int wave = tid >> 6, lane = tid & 63;
  const int grp = lane >> 4, lid = lane & 15;
  const int row0 = blockIdx.x * 64;
  const int node = blockIdx.y;
  const f16* WT = W1T_all + (size_t)node * HPAD * 256;  // [64][256]
  const int sr = tid >> 3, sc = (tid & 7) * 8;

  f32x4 acc[4] = {};
  for (int kt = 0; kt < 4; ++kt) {
    const int kb = kt * 64;
#pragma unroll
    for (int p = 0; p < 2; ++p)
      *(f16x8*)&At[p * 32 + sr][sc] =
          *(const f16x8*)&emb[(size_t)(row0 + p * 32 + sr) * 256 + kb + sc];
#pragma unroll
    for (int p = 0; p < 2; ++p)
      *(f16x8*)&Bt[p * 32 + sr][sc] =
          *(const f16x8*)&WT[(size_t)(p * 32 + sr) * 256 + kb + sc];
    __syncthreads();
#pragma unroll
    for (int kk = 0; kk < 2; ++kk) {
      f16x8 bf = *(const f16x8*)&Bt[wave * 16 + lid][kk * 32 + grp * 8];
#pragma unroll
      for (int m = 0; m < 4; ++m) {
        f16x8 af = *(const f16x8*)&At[m * 16 + lid][kk * 32 + grp * 8];
        acc[m] = mfma16(af, bf, acc[m]);
      }
    }
    __syncthreads();
  }
  const int col = wave * 16 + lid;
  const float bv = (col < HDIM) ? b1_all[node * HDIM + col] : 0.f;
#pragma unroll
  for (int m = 0; m < 4; ++m)
#pragma unroll
    for (int r = 0; r < 4; ++r) {
      const int row = row0 + m * 16 + grp * 4 + r;
      float v = acc[m][r] + bv;
      h_all[((size_t)node * B_ROWS + row) * HPAD + col] = (f16)(v > 0.f ? v : 0.f);
    }
}

// ---------------- inner stage 2: gates ----------------
// logits = h @ Ww + bw ; softmax over 256 ; t = softmax . x ; pR = sigmoid(beta*(t+b))
__global__ __launch_bounds__(256) void k_gate(const f16* __restrict__ h_all,
    const f16* __restrict__ WwT_all, const f16* __restrict__ x_h,
    const float* __restrict__ bw_all, const float* __restrict__ Wb_all,
    const float* __restrict__ bb_all, const float* __restrict__ Wbeta_all,
    const float* __restrict__ bbeta_all, float* __restrict__ pR) {
  __shared__ f16 ht[32][72];
  __shared__ f16 Wt[256][72];
  __shared__ f16 xt[32][264];
  __shared__ float bbuf[32], betabuf[32];
  __shared__ float red[4][32][2];
  const int tid = threadIdx.x;
  const int wave = tid >> 6, lane = tid & 63;
  const int grp = lane >> 4, lid = lane & 15;
  const int row0 = blockIdx.x * 32;
  const int node = blockIdx.y;
  const f16* WT = WwT_all + (size_t)node * 256 * HPAD;  // [256][64]
  {
    const int sr = tid >> 3, sc = (tid & 7) * 8;
    *(f16x8*)&ht[sr][sc] =
        *(const f16x8*)&h_all[((size_t)node * B_ROWS + row0 + sr) * HPAD + sc];
#pragma unroll
    for (int p = 0; p < 8; ++p)
      *(f16x8*)&Wt[p * 32 + sr][sc] =
          *(const f16x8*)&WT[(size_t)(p * 32 + sr) * HPAD + sc];
    const int xr = tid >> 5, xc = (tid & 31) * 8;
#pragma unroll
    for (int p = 0; p < 4; ++p)
      *(f16x8*)&xt[p * 8 + xr][xc] =
          *(const f16x8*)&x_h[(size_t)(row0 + p * 8 + xr) * 256 + xc];
  }
  __syncthreads();
  // b and beta dots (rows handled by first 32 threads)
  if (tid < 32) {
    float sb = 0.f, sbt = 0.f;
    const float* Wb = Wb_all + node * HDIM;
    const float* Wbt = Wbeta_all + node * HDIM;
    for (int hh = 0; hh < HDIM; ++hh) {
      float hv = (float)ht[tid][hh];
      sb += hv * Wb[hh];
      sbt += hv * Wbt[hh];
    }
    bbuf[tid] = sb + bb_all[node];
    betabuf[tid] = sbt + bbeta_all[node];
  }
  // logits GEMM: [32 rows] x [256 cols], K=64
  f32x4 acc[2][4] = {};
#pragma unroll
  for (int kk = 0; kk < 2; ++kk) {
    f16x8 af[2], bf[4];
#pragma unroll
    for (int m = 0; m < 2; ++m) af[m] = *(const f16x8*)&ht[m * 16 + lid][kk * 32 + grp * 8];
#pragma unroll
    for (int n = 0; n < 4; ++n) bf[n] = *(const f16x8*)&Wt[wave * 64 + n * 16 + lid][kk * 32 + grp * 8];
#pragma unroll
    for (int m = 0; m < 2; ++m)
#pragma unroll
      for (int n = 0; n < 4; ++n) acc[m][n] = mfma16(af[m], bf[n], acc[m][n]);
  }
  float lg[2][4][4];
#pragma unroll
  for (int n = 0; n < 4; ++n) {
    const int col = wave * 64 + n * 16 + lid;
    const float bwv = bw_all[node * 256 + col];
#pragma unroll
    for (int m = 0; m < 2; ++m)
#pragma unroll
      for (int r = 0; r < 4; ++r) lg[m][n][r] = acc[m][n][r] + bwv;
  }
  // row max over 256
  float rm[8];
#pragma unroll
  for (int m = 0; m < 2; ++m)
#pragma unroll
    for (int r = 0; r < 4; ++r) {
      float v = fmaxf(fmaxf(lg[m][0][r], lg[m][1][r]), fmaxf(lg[m][2][r], lg[m][3][r]));
      rm[m * 4 + r] = v;
    }
#pragma unroll
  for (int mask = 1; mask < 16; mask <<= 1)
#pragma unroll
    for (int i = 0; i < 8; ++i) rm[i] = fmaxf(rm[i], __shfl_xor(rm[i], mask, 64));
  if (lid == 0)
#pragma unroll
    for (int m = 0; m < 2; ++m)
#pragma unroll
      for (int r = 0; r < 4; ++r) red[wave][m * 16 + grp * 4 + r][0] = rm[m * 4 + r];
  __syncthreads();
#pragma unroll
  for (int m = 0; m < 2; ++m)
#pragma unroll
    for (int r = 0; r < 4; ++r) {
      const int row = m * 16 + grp * 4 + r;
      rm[m * 4 + r] = fmaxf(fmaxf(red[0][row][0], red[1][row][0]),
                            fmaxf(red[2][row][0], red[3][row][0]));
    }
  __syncthreads();
  // exp, sum, dot-with-x
  float s[8], dt[8];
#pragma unroll
  for (int i = 0; i < 8; ++i) { s[i] = 0.f; dt[i] = 0.f; }
#pragma unroll
  for (int m = 0; m < 2; ++m)
#pragma unroll
    for (int r = 0; r < 4; ++r) {
      const int row = m * 16 + grp * 4 + r;
#pragma unroll
      for (int n = 0; n < 4; ++n) {
        const int col = wave * 64 + n * 16 + lid;
        float e = __expf(lg[m][n][r] - rm[m * 4 + r]);
        s[m * 4 + r] += e;
        dt[m * 4 + r] += e * (float)xt[row][col];
      }
    }
#pragma unroll
  for (int mask = 1; mask < 16; mask <<= 1)
#pragma unroll
    for (int i = 0; i < 8; ++i) {
      s[i] += __shfl_xor(s[i], mask, 64);
      dt[i] += __shfl_xor(dt[i], mask, 64);
    }
  if (lid == 0)
#pragma unroll
    for (int m = 0; m < 2; ++m)
#pragma unroll
      for (int r = 0; r < 4; ++r) {
        red[wave][m * 16 + grp * 4 + r][0] = s[m * 4 + r];
        red[wave][m * 16 + grp * 4 + r][1] = dt[m * 4 + r];
      }
  __syncthreads();
  if (wave == 0 && lid == 0) {
#pragma unroll
    for (int m = 0; m < 2; ++m)
#pragma unroll
      for (int r = 0; r < 4; ++r) {
        const int row = m * 16 + grp * 4 + r;
        float S = red[0][row][0] + red[1][row][0] + red[2][row][0] + red[3][row][0];
        float DT = red[0][row][1] + red[1][row][1] + red[2][row][1] + red[3][row][1];
        float t = DT / S;
        float z = betabuf[row] * (t + bbuf[row]);
        pR[(size_t)(row0 + row) * 32 + node] = 1.f / (1.f + __expf(-z));
      }
  }
}

// ---------------- combine: heap walk over 31 gates, weighted sum of 32 leaves ----------------
__global__ void k_combine(const float* __restrict__ pR, const float* __restrict__ y_leaf,
                          float* __restrict__ out) {
  const int b = blockIdx.x * 256 + threadIdx.x;
  float p[32], y[32];
  const float4* pp = (const float4*)(pR + (size_t)b * 32);
  const float4* yp = (const float4*)(y_leaf + (size_t)b * 32);
#pragma unroll
  for (int i = 0; i < 8; ++i) {
    float4 v = pp[i]; p[i*4] = v.x; p[i*4+1] = v.y; p[i*4+2] = v.z; p[i*4+3] = v.w;
    float4 w = yp[i]; y[i*4] = w.x; y[i*4+1] = w.y; y[i*4+2] = w.z; y[i*4+3] = w.w;
  }
  float o = 0.f;
#pragma unroll
  for (int l = 0; l < 32; ++l) {
    float pr = 1.f;
    int node = 0;
#pragma unroll
    for (int k = 0; k < 5; ++k) {
      const int bit = (l >> (4 - k)) & 1;
      const float pv = p[node];
      pr *= bit ? pv : (1.f - pv);
      node = 2 * node + 1 + bit;
    }
    o += pr * y[l];
  }
  out[b] = o;
}

extern "C" void kernel_launch(void* const* d_in, const int* in_sizes, int n_in,
                              void* d_out, int out_size, void* d_ws, size_t ws_size,
                              hipStream_t stream) {
  (void)in_sizes; (void)n_in; (void)out_size; (void)ws_size;
  const float* x        = (const float*)d_in[0];
  const float* enc_W    = (const float*)d_in[1];
  const float* enc_b    = (const float*)d_in[2];
  const float* in_W1    = (const float*)d_in[3];
  const float* in_b1    = (const float*)d_in[4];
  const float* in_Ww    = (const float*)d_in[5];
  const float* in_bw    = (const float*)d_in[6];
  const float* in_Wb    = (const float*)d_in[7];
  const float* in_bb    = (const float*)d_in[8];
  const float* in_Wbeta = (const float*)d_in[9];
  const float* in_bbeta = (const float*)d_in[10];
  const float* lf_W1    = (const float*)d_in[11];
  const float* lf_b1    = (const float*)d_in[12];
  const float* lf_W2    = (const float*)d_in[13];
  const float* lf_b2    = (const float*)d_in[14];
  float* out = (float*)d_out;

  char* ws = (char*)d_ws;
  f16* x_h     = (f16*)(ws);               // 8192*256*2      = 4 MB
  f16* emb0    = (f16*)(ws + 4194304);     // 4 MB
  f16* emb1    = (f16*)(ws + 8388608);     // 4 MB
  f16* encWT   = (f16*)(ws + 12582912);    // 4*256*256*2     = 512 KB
  f16* lfW1T   = (f16*)(ws + 13107200);    // 32*256*256*2    = 4 MB
  f16* inW1T   = (f16*)(ws + 17301504);    // 31*64*256*2     = ~1 MB
  f16* inWwT   = (f16*)(ws + 18317312);    // 31*256*64*2     = ~1 MB
  f16* h_all   = (f16*)(ws + 19333120);    // 31*8192*64*2    = 31 MB
  float* pR      = (float*)(ws + 51838976); // 8192*32*4 = 1 MB
  float* y_leaf  = (float*)(ws + 52887552); // 8192*32*4 = 1 MB

  dim3 tb(32, 8);
  hipLaunchKernelGGL(k_cast_f16, dim3(2048), dim3(256), 0, stream, x, x_h, B_ROWS * 256 / 4);
  hipLaunchKernelGGL(k_tcast, dim3(8, 8, 4),  tb, 0, stream, enc_W, encWT, 256, 256, 256, 256);
  hipLaunchKernelGGL(k_tcast, dim3(8, 8, 32), tb, 0, stream, lf_W1, lfW1T, 256, 256, 256, 256);
  hipLaunchKernelGGL(k_tcast, dim3(8, 2, 31), tb, 0, stream, in_W1, inW1T, 256, 50, 256, 64);
  hipLaunchKernelGGL(k_tcast, dim3(2, 8, 31), tb, 0, stream, in_Ww, inWwT, 50, 256, 64, 256);

  hipLaunchKernelGGL(k_enc, dim3(128), dim3(256), 0, stream, x_h,  encWT + 0 * 65536, enc_b + 0,   emb0);
  hipLaunchKernelGGL(k_enc, dim3(128), dim3(256), 0, stream, emb0, encWT + 1 * 65536, enc_b + 256, emb1);
  hipLaunchKernelGGL(k_enc, dim3(128), dim3(256), 0, stream, emb1, encWT + 2 * 65536, enc_b + 512, emb0);
  hipLaunchKernelGGL(k_enc, dim3(128), dim3(256), 0, stream, emb0, encWT + 3 * 65536, enc_b + 768, emb1);

  hipLaunchKernelGGL(k_hnode, dim3(128, 31), dim3(256), 0, stream, emb1, inW1T, in_b1, h_all);
  hipLaunchKernelGGL(k_gate, dim3(256, 31), dim3(256), 0, stream, h_all, inWwT, x_h,
                     in_bw, in_Wb, in_bb, in_Wbeta, in_bbeta, pR);
  hipLaunchKernelGGL(k_leaf, dim3(128, 32), dim3(256), 0, stream, emb1, lfW1T, lf_b1, lf_W2, lf_b2, y_leaf);
  hipLaunchKernelGGL(k_combine, dim3(32), dim3(256), 0, stream, pR, y_leaf, out);
}